// Round 9
// baseline (54.813 us; speedup 1.0000x reference)
//
#include <hip/hip_runtime.h>
#include <hip/hip_bf16.h>

#define B_     32
#define N_     16384
#define D_     64
#define C_     36
#define CP_    48     // padded cluster count (3 x 16 MFMA tiles)
#define FG_    32
#define ALPHA_ 10.0f
#define NB_    32     // n-blocks per batch -> grid 1024 = 4 blocks/CU
#define RPB_   (N_/NB_)   // 512 rows per block

typedef __attribute__((ext_vector_type(8))) short bf16x8;
typedef __attribute__((ext_vector_type(4))) short bf16x4;
typedef __attribute__((ext_vector_type(4))) float f32x4;

#define MFMA(a,b,c) __builtin_amdgcn_mfma_f32_16x16x32_bf16(a,b,c,0,0,0)

// float -> bf16 bits via native conversion (v_cvt_pk_bf16_f32, RNE on gfx950).
__device__ __forceinline__ short bfbits(float v){
  __bf16 h = (__bf16)v;
  return __builtin_bit_cast(short, h);
}
__device__ __forceinline__ float bfval(short u){
  return __uint_as_float(((unsigned)(unsigned short)u) << 16);
}

// v -> hi bf16 (slot J of H) + residual lo bf16 (slot J of L)
#define CVT1(v, H, L, J) { short hb_ = bfbits(v); (H)[J] = hb_; \
  (L)[J] = bfbits((v) - bfval(hb_)); }

__device__ __forceinline__ bf16x8 ld_frag(const unsigned short* p){
  bf16x4 a = *(const bf16x4*)p;
  bf16x4 b = *(const bf16x4*)(p + 4);
  return __builtin_shufflevector(a, b, 0,1,2,3,4,5,6,7);
}

// ---------------------------------------------------------------------------
// Fused kernel. grid = 1024 (32 batches x 32 n-blocks), block = 256 = 4 waves.
// Wave owns 128 rows = 8 groups of 16; ws-GEMM after each odd group.
// Depth-3 rolling prefetch (A/B/C buffers over hand-rolled 8-group sequence):
// ~2 group-chains of latency cover (~1300 cyc >= ~900 cyc HBM).
// Per 16-row group: row norm -> bf16 hi/lo frags -> cos MFMA -> softmax ->
//   asg/x^T staged to LDS (transposed layout, pitch 36).
// self_product recovered in k_red1 via identity sp[c] = sum_d cn[d,c]*ws[d,c].
// NPART==NB_: non-atomic per-block partials; NPART==1: atomic fallback.
// ---------------------------------------------------------------------------
template<int NPART>
__global__ __launch_bounds__(256, 4) void k_accum(
    const float* __restrict__ x, const float* __restrict__ cent,
    float* __restrict__ wsP)
{
  const int t   = threadIdx.x;
  const int wid = t >> 6;
  const int l   = t & 63;
  const int lm  = l & 15;
  const int lg  = l >> 4;
  const int b   = blockIdx.x >> 5;
  const int nb  = blockIdx.x & 31;

  __shared__ float nrmc[C_];
  __shared__ __align__(16) union {
    struct { unsigned short asg[4][CP_*36]; unsigned short xt[4][64*36]; } m; // 32256 B
    float red[2][CP_*65];                                                     // 24960 B
  } sh;

  if (t < C_) {
    float ss = 0.f;
    for (int d = 0; d < D_; ++d) { float v = cent[d*C_ + t]; ss = fmaf(v, v, ss); }
    nrmc[t] = rsqrtf(fmaxf(ss, 1e-24f));
  }
  __syncthreads();

  // normalized-centroid A-fragments: A[m=c][k=d], c = 16*ct+lm, d = 32*s+8*lg+j
  bf16x8 cnf[3][2];
  #pragma unroll
  for (int ct = 0; ct < 3; ++ct) {
    #pragma unroll
    for (int s = 0; s < 2; ++s) {
      bf16x8 f;
      #pragma unroll
      for (int j = 0; j < 8; ++j) {
        int d = 32*s + 8*lg + j;
        int c = 16*ct + lm;
        float v = (c < C_) ? cent[d*C_ + c] * nrmc[c] : 0.f;
        f[j] = bfbits(v);
      }
      cnf[ct][s] = f;
    }
  }

  f32x4 acc[3][4];
  #pragma unroll
  for (int ct = 0; ct < 3; ++ct)
    #pragma unroll
    for (int nt = 0; nt < 4; ++nt) acc[ct][nt] = (f32x4){0.f,0.f,0.f,0.f};

  unsigned short* aw = sh.m.asg[wid];
  unsigned short* xw = sh.m.xt[wid];

  // per-16-row-group staging: lane holds row lm, float cols {8lg..+7, 32+8lg..+7}
  auto process = [&](float4 c0, float4 c1, float4 c2, float4 c3, int g2) {
    float ss = 0.f;
    ss = fmaf(c0.x,c0.x,ss); ss = fmaf(c0.y,c0.y,ss); ss = fmaf(c0.z,c0.z,ss); ss = fmaf(c0.w,c0.w,ss);
    ss = fmaf(c1.x,c1.x,ss); ss = fmaf(c1.y,c1.y,ss); ss = fmaf(c1.z,c1.z,ss); ss = fmaf(c1.w,c1.w,ss);
    ss = fmaf(c2.x,c2.x,ss); ss = fmaf(c2.y,c2.y,ss); ss = fmaf(c2.z,c2.z,ss); ss = fmaf(c2.w,c2.w,ss);
    ss = fmaf(c3.x,c3.x,ss); ss = fmaf(c3.y,c3.y,ss); ss = fmaf(c3.z,c3.z,ss); ss = fmaf(c3.w,c3.w,ss);
    ss += __shfl_xor(ss, 16);
    ss += __shfl_xor(ss, 32);
    float rn = rsqrtf(fmaxf(ss, 1e-24f));

    bf16x8 bh0, bl0, bh1, bl1;
    CVT1(c0.x,bh0,bl0,0) CVT1(c0.y,bh0,bl0,1) CVT1(c0.z,bh0,bl0,2) CVT1(c0.w,bh0,bl0,3)
    CVT1(c1.x,bh0,bl0,4) CVT1(c1.y,bh0,bl0,5) CVT1(c1.z,bh0,bl0,6) CVT1(c1.w,bh0,bl0,7)
    CVT1(c2.x,bh1,bl1,0) CVT1(c2.y,bh1,bl1,1) CVT1(c2.z,bh1,bl1,2) CVT1(c2.w,bh1,bl1,3)
    CVT1(c3.x,bh1,bl1,4) CVT1(c3.y,bh1,bl1,5) CVT1(c3.z,bh1,bl1,6) CVT1(c3.w,bh1,bl1,7)

    // cos GEMM: D[m=c][n=row] = cn . x (raw x; rn applied in softmax arg)
    f32x4 q0 = (f32x4){0,0,0,0}, q1 = (f32x4){0,0,0,0}, q2 = (f32x4){0,0,0,0};
    q0 = MFMA(cnf[0][0], bh0, q0); q0 = MFMA(cnf[0][1], bh1, q0);
    q0 = MFMA(cnf[0][0], bl0, q0); q0 = MFMA(cnf[0][1], bl1, q0);
    q1 = MFMA(cnf[1][0], bh0, q1); q1 = MFMA(cnf[1][1], bh1, q1);
    q1 = MFMA(cnf[1][0], bl0, q1); q1 = MFMA(cnf[1][1], bl1, q1);
    q2 = MFMA(cnf[2][0], bh0, q2); q2 = MFMA(cnf[2][1], bh1, q2);
    q2 = MFMA(cnf[2][0], bl0, q2); q2 = MFMA(cnf[2][1], bl1, q2);
    f32x4 q[3] = {q0, q1, q2};

    // softmax over c; lane holds c = 16ct+4lg+r for row = lm (+16*g2)
    float e[3][4]; float psum = 0.f;
    #pragma unroll
    for (int ct = 0; ct < 3; ++ct)
      #pragma unroll
      for (int r = 0; r < 4; ++r) {
        int c = 16*ct + 4*lg + r;
        float ev = (c < C_) ? __expf(ALPHA_ * rn * q[ct][r]) : 0.f;
        e[ct][r] = ev; psum += ev;
      }
    psum += __shfl_xor(psum, 16);
    psum += __shfl_xor(psum, 32);
    float arn = rn / psum;               // (assign * rn) scale

    const int rowin = g2*16 + lm;        // row within 32-row unit
    #pragma unroll
    for (int ct = 0; ct < 3; ++ct)
      #pragma unroll
      for (int r = 0; r < 4; ++r)
        aw[(16*ct + 4*lg + r)*36 + rowin] = (unsigned short)bfbits(e[ct][r] * arn);
    #pragma unroll
    for (int j = 0; j < 8; ++j) {
      xw[(     8*lg + j)*36 + rowin] = (unsigned short)bh0[j];     // xt[d][row]
      xw[(32 + 8*lg + j)*36 + rowin] = (unsigned short)bh1[j];
    }
  };

  // ws GEMM over the current 32-row unit (wave-local LDS, compiler-ordered)
  auto wsgemm = [&]() {
    bf16x8 af0 = ld_frag(&aw[( 0 + lm)*36 + 8*lg]);
    bf16x8 af1 = ld_frag(&aw[(16 + lm)*36 + 8*lg]);
    bf16x8 af2 = ld_frag(&aw[(32 + lm)*36 + 8*lg]);
    #pragma unroll
    for (int nt = 0; nt < 4; ++nt) {
      bf16x8 xf = ld_frag(&xw[(16*nt + lm)*36 + 8*lg]);
      acc[0][nt] = MFMA(af0, xf, acc[0][nt]);
      acc[1][nt] = MFMA(af1, xf, acc[1][nt]);
      acc[2][nt] = MFMA(af2, xf, acc[2][nt]);
    }
  };

  const float* px = x + ((size_t)b*N_ + (size_t)nb*RPB_ + wid*128 + lm)*D_ + lg*8;

  #define LOADG(P0,P1,P2,P3,G) { const float* p_ = px + (size_t)(G)*1024; \
    P0=*(const float4*)p_; P1=*(const float4*)(p_+4); P2=*(const float4*)(p_+32); P3=*(const float4*)(p_+36); }

  // Depth-3 rotation A/B/C over 8 groups; ws-GEMM after each odd group.
  float4 A0,A1,A2,A3, B0,B1,B2,B3, C0,C1,C2,C3;
  LOADG(A0,A1,A2,A3, 0)
  LOADG(B0,B1,B2,B3, 1)
  LOADG(C0,C1,C2,C3, 2)

  process(A0,A1,A2,A3, 0); LOADG(A0,A1,A2,A3, 3)
  process(B0,B1,B2,B3, 1); LOADG(B0,B1,B2,B3, 4)  wsgemm();
  process(C0,C1,C2,C3, 0); LOADG(C0,C1,C2,C3, 5)
  process(A0,A1,A2,A3, 1); LOADG(A0,A1,A2,A3, 6)  wsgemm();
  process(B0,B1,B2,B3, 0); LOADG(B0,B1,B2,B3, 7)
  process(C0,C1,C2,C3, 1);                        wsgemm();
  process(A0,A1,A2,A3, 0);
  process(B0,B1,B2,B3, 1);                        wsgemm();
  #undef LOADG

  // ---- epilogue: combine 4 waves' acc in LDS, write per-block partials ----
  __syncthreads();                       // all waves done with sh.m (union reuse)
  if (wid < 2) {
    #pragma unroll
    for (int ct = 0; ct < 3; ++ct)
      #pragma unroll
      for (int nt = 0; nt < 4; ++nt)
        #pragma unroll
        for (int r = 0; r < 4; ++r)
          sh.red[wid][(16*ct + 4*lg + r)*65 + 16*nt + lm] = acc[ct][nt][r];
  }
  __syncthreads();
  if (wid >= 2) {
    #pragma unroll
    for (int ct = 0; ct < 3; ++ct)
      #pragma unroll
      for (int nt = 0; nt < 4; ++nt)
        #pragma unroll
        for (int r = 0; r < 4; ++r)
          sh.red[wid-2][(16*ct + 4*lg + r)*65 + 16*nt + lm] += acc[ct][nt][r];
  }
  __syncthreads();

  if (NPART == NB_) {
    const size_t blk = blockIdx.x;
    for (int i = t; i < C_*D_; i += 256) {
      int c = i >> 6, d = i & 63;
      wsP[blk*(C_*D_) + i] = sh.red[0][c*65 + d] + sh.red[1][c*65 + d];
    }
  } else {
    for (int i = t; i < C_*D_; i += 256) {
      int c = i >> 6, d = i & 63;
      atomicAdd(&wsP[(size_t)b*(C_*D_) + i], sh.red[0][c*65 + d] + sh.red[1][c*65 + d]);
    }
  }
}

// ---------------------------------------------------------------------------
// Reduce + finalize: grid = B_*FG_ (1024 blocks) x 256 threads; 4 k-quarters
// per (b,c) reduced via LDS. s(d) = sum_k wsP; sp = sum_d cn*s (identity);
// v = s - cn*sp; out = v/||v|| * 1/sqrt(C_) (all C_ rows unit-norm => global
// norm is analytic).
// ---------------------------------------------------------------------------
template<int NPART>
__global__ __launch_bounds__(256) void k_red1(
    const float* __restrict__ cent, const float* __restrict__ wsP,
    float* __restrict__ out)
{
  const int bc = blockIdx.x;
  const int b  = bc >> 5;        // / FG_
  const int c  = bc & 31;        // % FG_
  const int t  = threadIdx.x;
  const int d  = t & 63;
  const int kq = t >> 6;         // k-quarter

  __shared__ float pr[4][64];

  float s = 0.f;
  for (int k = kq; k < NPART; k += 4)
    s += wsP[((size_t)b*NPART + k)*(C_*D_) + c*D_ + d];
  pr[kq][d] = s;
  __syncthreads();

  if (t < 64) {
    s = pr[0][d] + pr[1][d] + pr[2][d] + pr[3][d];

    // normalized centroid component cn[d][c]
    float cv = cent[d*C_ + c];
    float cs = cv*cv;
    #pragma unroll
    for (int off = 32; off; off >>= 1) cs += __shfl_xor(cs, off);
    float cn = cv * rsqrtf(fmaxf(cs, 1e-24f));

    // self-product via identity sp = sum_d cn*ws
    float spv = cn * s;
    #pragma unroll
    for (int off = 32; off; off >>= 1) spv += __shfl_xor(spv, off);

    float v = s - cn * spv;
    float vs = v*v;
    #pragma unroll
    for (int off = 32; off; off >>= 1) vs += __shfl_xor(vs, off);

    const float rg = 0.16666666666666666f;   // 1/sqrt(C_): all C_ rows unit-norm
    out[(size_t)bc*D_ + d] = v * rsqrtf(fmaxf(vs, 1e-24f)) * rg;
  }
}

extern "C" void kernel_launch(void* const* d_in, const int* in_sizes, int n_in,
                              void* d_out, int out_size, void* d_ws, size_t ws_size,
                              hipStream_t stream) {
  const float* x    = (const float*)d_in[0];
  const float* cent = (const float*)d_in[1];
  float* out = (float*)d_out;

  const size_t nblk = (size_t)B_ * NB_;                 // 1024
  const size_t need = nblk*(C_*D_) * sizeof(float);     // ~9.4 MB

  if (ws_size >= need) {
    float* wsP = (float*)d_ws;                          // [1024][2304]
    k_accum<NB_><<<B_*NB_, 256, 0, stream>>>(x, cent, wsP);
    k_red1<NB_><<<B_*FG_, 256, 0, stream>>>(cent, wsP, out);
  } else {                                              // atomic fallback
    float* wsA = (float*)d_ws;                          // [32][2304]
    hipMemsetAsync(d_ws, 0, (size_t)B_*(C_*D_)*sizeof(float), stream);
    k_accum<1><<<B_*NB_, 256, 0, stream>>>(x, cent, wsA);
    k_red1<1><<<B_*FG_, 256, 0, stream>>>(cent, wsA, out);
  }
}